// Round 1
// baseline (36588.840 us; speedup 1.0000x reference)
//
#include <hip/hip_runtime.h>
#include <hip/hip_bf16.h>
#include <hip/hip_cooperative_groups.h>

#define B_ 64
#define T_ 512
#define D_ 512
#define H_ 1024
#define G_ 4096        // 4*H
#define K_ 1536        // D + H
#define KP 1544        // LDS k-stride (bf16 elems), padded: 3088B %128B != 0 -> 2-way max bank aliasing
#define NJ 8           // h-columns per workgroup
#define NW 32          // z-columns per workgroup (4 gates * NJ)
#define NSTEPS 512
#define WG_COUNT 256   // 2 dirs * 128 wgs
#define LDS_W_BYTES (NW * KP * 2)            // 98816
#define LDS_C_BYTES (64 * 33 * 4)            // 8448 (padded C tile)
#define LDS_TOTAL   (LDS_W_BYTES + LDS_C_BYTES)

typedef unsigned short u16;
typedef __bf16 v8bf __attribute__((ext_vector_type(8)));
typedef float  v4f  __attribute__((ext_vector_type(4)));

__device__ __forceinline__ u16 f2bf(float f) {
    unsigned u = __builtin_bit_cast(unsigned, f);
    u += 0x7fffu + ((u >> 16) & 1u);   // RNE
    return (u16)(u >> 16);
}
__device__ __forceinline__ float sigm(float x) { return 1.0f / (1.0f + __expf(-x)); }
__device__ __forceinline__ float tanh_f(float x) { return 1.0f - 2.0f / (__expf(2.0f * x) + 1.0f); }

// ---------------- pre-pass: inputs [B,T,D] fp32 -> xT [T,B,D] bf16 ----------------
__global__ void cvt_x_kernel(const float* __restrict__ xin, u16* __restrict__ xT) {
    int gid = blockIdx.x * 256 + threadIdx.x;       // over B*T*(D/4)
    int d0 = (gid & 127) * 4;
    int bt = gid >> 7;                               // b*T + t
    int b = bt >> 9;
    int t = bt & 511;
    float4 v = *(const float4*)(xin + (size_t)bt * D_ + d0);
    ushort4 o;
    o.x = f2bf(v.x); o.y = f2bf(v.y); o.z = f2bf(v.z); o.w = f2bf(v.w);
    *(ushort4*)(xT + ((size_t)t * B_ + b) * D_ + d0) = o;
}

// ---------------- persistent cooperative scan kernel ----------------
// grid = 256 wgs: wg&1 = dir, wg>>1 = j-group (8 h-cols). 256 threads = 4 waves.
// LDS: W slice [NW][KP] bf16 (resident all steps, B^T layout) + C tile [64][33] f32.
// h double-buffered in ws by step parity: hb[parity][dir][B][H] bf16.
extern "C" __global__ void __launch_bounds__(256, 1)
scan_kernel(const float* __restrict__ Wx_f, const float* __restrict__ Wh_f,
            const float* __restrict__ b_f,
            const float* __restrict__ Wx_b, const float* __restrict__ Wh_b,
            const float* __restrict__ b_b,
            const u16* __restrict__ xT, u16* __restrict__ hb,
            float* __restrict__ out) {
    extern __shared__ char smem[];
    u16*   Wlds = (u16*)smem;
    float* Clds = (float*)(smem + LDS_W_BYTES);

    const int tid  = threadIdx.x;
    const int wg   = blockIdx.x;
    const int dir  = wg & 1;
    const int wid  = wg >> 1;       // 0..127
    const int j0   = wid * NJ;

    const float* Wx   = dir ? Wx_b : Wx_f;
    const float* Wh   = dir ? Wh_b : Wh_f;
    const float* bias = dir ? b_b  : b_f;

    // --- stage W slice into LDS (one-time), B^T layout: Wlds[n][k] = W[k][zcol(n)] ---
    for (int n = 0; n < NW; ++n) {
        int zc = (n >> 3) * H_ + j0 + (n & 7);
        for (int k = tid; k < K_; k += 256) {
            float w = (k < D_) ? Wx[(size_t)k * G_ + zc]
                               : Wh[(size_t)(k - D_) * G_ + zc];
            Wlds[n * KP + k] = f2bf(w);
        }
    }

    // --- zero parity-0 h buffer (ws is poisoned every call): 256KB spread over grid ---
    ((unsigned int*)hb)[wg * 256 + tid] = 0u;

    // --- per-thread constants ---
    const int lane = tid & 63;
    const int wv   = tid >> 6;       // wave 0..3
    const int quad = lane >> 4;
    const int l15  = lane & 15;
    const int p    = wv & 1;         // m-pair (rows p*32 .. p*32+31)
    const int nt   = wv >> 1;        // n-tile (cols nt*16 .. nt*16+15)

    // epilogue ownership: idx = tid*2+e -> (b, jj)
    const int jj0 = (tid * 2) & 7, jj1 = (tid * 2 + 1) & 7;
    const float bi0 = bias[j0 + jj0],        bi1 = bias[j0 + jj1];
    const float bf0 = bias[H_ + j0 + jj0],   bf1 = bias[H_ + j0 + jj1];
    const float bo0 = bias[2*H_ + j0 + jj0], bo1 = bias[2*H_ + j0 + jj1];
    const float bg0 = bias[3*H_ + j0 + jj0], bg1 = bias[3*H_ + j0 + jj1];

    const u16* Bp = Wlds + (nt * 16 + l15) * KP + quad * 8;

    cooperative_groups::this_grid().sync();   // W staged + h0 zeroed everywhere

    float cst0 = 0.0f, cst1 = 0.0f;           // c-state for the 2 owned (b,j) pairs

    for (int s = 0; s < NSTEPS; ++s) {
        const int t  = dir ? (T_ - 1 - s) : s;
        const int pr = s & 1;                  // read parity
        const int pw = pr ^ 1;                 // write parity

        v4f acc0 = {0.f, 0.f, 0.f, 0.f};
        v4f acc1 = {0.f, 0.f, 0.f, 0.f};

        const u16* Ax = xT + ((size_t)t * B_ + p * 32 + l15) * D_ + quad * 8;
        const u16* Ah = hb + (((size_t)pr * 2 + dir) * B_ + p * 32 + l15) * H_ + quad * 8;

        // K-part 1: x projection (k = 0..511)
        #pragma unroll
        for (int kt = 0; kt < 16; ++kt) {
            v8bf a0 = *(const v8bf*)(Ax + kt * 32);
            v8bf a1 = *(const v8bf*)(Ax + 16 * D_ + kt * 32);
            v8bf bb = *(const v8bf*)(Bp + kt * 32);
            acc0 = __builtin_amdgcn_mfma_f32_16x16x32_bf16(a0, bb, acc0, 0, 0, 0);
            acc1 = __builtin_amdgcn_mfma_f32_16x16x32_bf16(a1, bb, acc1, 0, 0, 0);
        }
        // K-part 2: h recurrence (k = 512..1535)
        #pragma unroll 16
        for (int kt = 0; kt < 32; ++kt) {
            v8bf a0 = *(const v8bf*)(Ah + kt * 32);
            v8bf a1 = *(const v8bf*)(Ah + 16 * H_ + kt * 32);
            v8bf bb = *(const v8bf*)(Bp + D_ + kt * 32);
            acc0 = __builtin_amdgcn_mfma_f32_16x16x32_bf16(a0, bb, acc0, 0, 0, 0);
            acc1 = __builtin_amdgcn_mfma_f32_16x16x32_bf16(a1, bb, acc1, 0, 0, 0);
        }

        // write C tile to LDS (padded stride 33 -> conflict-free)
        #pragma unroll
        for (int r = 0; r < 4; ++r) {
            Clds[(p * 32 + quad * 4 + r) * 33 + nt * 16 + l15]      = acc0[r];
            Clds[(p * 32 + 16 + quad * 4 + r) * 33 + nt * 16 + l15] = acc1[r];
        }
        __syncthreads();

        // epilogue: each thread owns (b,j) pairs idx = tid*2, tid*2+1
        {
            int idx = tid * 2;
            int b = idx >> 3, jj = idx & 7;
            float iv = sigm(Clds[b * 33 + jj]      + bi0);
            float fv = sigm(Clds[b * 33 + 8 + jj]  + bf0);
            float ov = sigm(Clds[b * 33 + 16 + jj] + bo0);
            float gv = tanh_f(Clds[b * 33 + 24 + jj] + bg0);
            float cv = fv * cst0 + iv * gv; cst0 = cv;
            float hv = ov * tanh_f(cv);
            int j = j0 + jj;
            hb[(((size_t)pw * 2 + dir) * B_ + b) * H_ + j] = f2bf(hv);
            out[((size_t)b * T_ + t) * (2 * H_) + dir * H_ + j] = hv;
        }
        {
            int idx = tid * 2 + 1;
            int b = idx >> 3, jj = idx & 7;
            float iv = sigm(Clds[b * 33 + jj]      + bi1);
            float fv = sigm(Clds[b * 33 + 8 + jj]  + bf1);
            float ov = sigm(Clds[b * 33 + 16 + jj] + bo1);
            float gv = tanh_f(Clds[b * 33 + 24 + jj] + bg1);
            float cv = fv * cst1 + iv * gv; cst1 = cv;
            float hv = ov * tanh_f(cv);
            int j = j0 + jj;
            hb[(((size_t)pw * 2 + dir) * B_ + b) * H_ + j] = f2bf(hv);
            out[((size_t)b * T_ + t) * (2 * H_) + dir * H_ + j] = hv;
        }

        __threadfence();                       // release h writes device-wide
        cooperative_groups::this_grid().sync();
    }
}

extern "C" void kernel_launch(void* const* d_in, const int* in_sizes, int n_in,
                              void* d_out, int out_size, void* d_ws, size_t ws_size,
                              hipStream_t stream) {
    const float* xin  = (const float*)d_in[0];
    const float* Wx_f = (const float*)d_in[1];
    const float* Wh_f = (const float*)d_in[2];
    const float* b_f  = (const float*)d_in[3];
    const float* Wx_b = (const float*)d_in[4];
    const float* Wh_b = (const float*)d_in[5];
    const float* b_b  = (const float*)d_in[6];
    float* out = (float*)d_out;

    u16* xT = (u16*)d_ws;                                  // T*B*D bf16 = 32 MiB
    u16* hb = (u16*)((char*)d_ws + (size_t)T_ * B_ * D_ * 2); // 2*2*B*H bf16 = 512 KiB

    hipLaunchKernelGGL(cvt_x_kernel, dim3((B_ * T_ * (D_ / 4)) / 256), dim3(256), 0, stream,
                       xin, xT);

    hipFuncSetAttribute(reinterpret_cast<const void*>(scan_kernel),
                        hipFuncAttributeMaxDynamicSharedMemorySize, LDS_TOTAL);

    void* args[] = {(void*)&Wx_f, (void*)&Wh_f, (void*)&b_f,
                    (void*)&Wx_b, (void*)&Wh_b, (void*)&b_b,
                    (void*)&xT, (void*)&hb, (void*)&out};
    hipLaunchCooperativeKernel(reinterpret_cast<void*>(scan_kernel),
                               dim3(WG_COUNT), dim3(256), args, LDS_TOTAL, stream);
}

// Round 2
// 6772.354 us; speedup vs baseline: 5.4027x; 5.4027x over previous
//
#include <hip/hip_runtime.h>
#include <hip/hip_bf16.h>

#define B_ 64
#define T_ 512
#define D_ 512
#define H_ 1024
#define G_ 4096
#define NJ 8               // j-columns per wg
#define WPD 128            // wgs per direction
#define WGS 256            // total wgs (1 per CU)
#define APE 520            // A-chunk row stride in u16 elems (1040 B = 1024 + 16 pad)
#define ABUF_B (64 * APE * 2)          // 66560 B per A chunk buffer
#define CT_OFF (2 * ABUF_B)            // 133120
#define LDS_TOTAL (CT_OFF + 2 * 64 * 33 * 4)   // 150016 B

typedef unsigned short u16;
typedef __bf16 v8bf __attribute__((ext_vector_type(8)));
typedef unsigned short v8us __attribute__((ext_vector_type(8)));
typedef float v4f __attribute__((ext_vector_type(4)));

#define MFMA(a, b, c) __builtin_amdgcn_mfma_f32_16x16x32_bf16(a, b, c, 0, 0, 0)

__device__ __forceinline__ u16 f2bf(float f) {
    unsigned u = __builtin_bit_cast(unsigned, f);
    u += 0x7fffu + ((u >> 16) & 1u);   // RNE
    return (u16)(u >> 16);
}
__device__ __forceinline__ float sigm(float x) { return 1.0f / (1.0f + __expf(-x)); }
__device__ __forceinline__ float tanh_f(float x) { return 1.0f - 2.0f / (__expf(2.0f * x) + 1.0f); }

// async global->LDS, 16B per lane; lds dst must be wave-uniform base (lane*16 implicit)
__device__ __forceinline__ void gl_lds(const u16* g, u16* l) {
    __builtin_amdgcn_global_load_lds(
        (const __attribute__((address_space(1))) unsigned int*)g,
        (__attribute__((address_space(3))) unsigned int*)l, 16, 0, 0);
}

// ---------------- pre-pass: convert x to [T,B,D] bf16, zero h0 + barrier counters ----------------
__global__ void prep_kernel(const float* __restrict__ xin, u16* __restrict__ xT,
                            u16* __restrict__ hb, int* __restrict__ cnt) {
    int gid = blockIdx.x * 256 + threadIdx.x;           // over B*T*(D/4) = 4.19M
    if (gid < 65536) ((unsigned int*)hb)[gid] = 0u;     // parity-0 h buffers (256 KB)
    if (gid < 8) cnt[gid] = 0;
    int d0 = (gid & 127) * 4;
    int bt = gid >> 7;
    int b = bt >> 9, t = bt & 511;
    float4 v = *(const float4*)(xin + (size_t)bt * D_ + d0);
    ushort4 o;
    o.x = f2bf(v.x); o.y = f2bf(v.y); o.z = f2bf(v.z); o.w = f2bf(v.w);
    *(ushort4*)(xT + ((size_t)t * B_ + b) * D_ + d0) = o;
}

// ---------------- persistent scan kernel ----------------
// 256 wgs x 512 threads (8 waves), 1 wg/CU, 2 waves/SIMD.
// wave w: nt=w&1 (16-col n-tile), mh=(w>>1)&1 (32-row half), kh=w>>2 (768-wide K half).
// W held in VGPRs (24 bf16x8 frags/lane). LDS: 2 A-chunk buffers + 2 partial C tiles.
extern "C" __global__ void __launch_bounds__(512, 2)
scan_kernel(const float* __restrict__ Wx_f, const float* __restrict__ Wh_f,
            const float* __restrict__ b_f,
            const float* __restrict__ Wx_b, const float* __restrict__ Wh_b,
            const float* __restrict__ b_b,
            const u16* __restrict__ xT, u16* __restrict__ hb,
            int* __restrict__ cnt, float* __restrict__ out) {
    extern __shared__ char smem[];
    u16* Ab0 = (u16*)smem;
    u16* Ab1 = (u16*)(smem + ABUF_B);
    float* Cl = (float*)(smem + CT_OFF);   // [2][64][33] f32 partials

    const int tid = threadIdx.x;
    const int wg  = blockIdx.x;
    const int dir = wg & 1;
    const int wid = wg >> 1;
    const int j0  = wid * NJ;

    const float* Wx   = dir ? Wx_b : Wx_f;
    const float* Wh   = dir ? Wh_b : Wh_f;
    const float* bias = dir ? b_b  : b_f;

    const int w    = tid >> 6;
    const int lane = tid & 63;
    const int quad = lane >> 4;
    const int l15  = lane & 15;
    const int nt = w & 1;
    const int mh = (w >> 1) & 1;
    const int kh = w >> 2;

    // ---- one-time: load W fragments into registers (B-operand: lane l15 = col) ----
    const int n  = nt * 16 + l15;
    const int zc = (n >> 3) * H_ + j0 + (n & 7);
    v8bf bfr[24];
    #pragma unroll
    for (int f = 0; f < 24; ++f) {
        const int kb = kh * 768 + f * 32 + quad * 8;
        v8us tmp;
        #pragma unroll
        for (int e = 0; e < 8; ++e) {
            int k = kb + e;
            float wv = (k < D_) ? Wx[(size_t)k * G_ + zc]
                                : Wh[(size_t)(k - D_) * G_ + zc];
            tmp[e] = f2bf(wv);
        }
        bfr[f] = __builtin_bit_cast(v8bf, tmp);
    }

    // epilogue ownership: 512 threads <-> 64 b x 8 jj
    const int ejj = tid & 7, eb = tid >> 3;
    const float bI = bias[j0 + ejj];
    const float bF = bias[H_ + j0 + ejj];
    const float bO = bias[2 * H_ + j0 + ejj];
    const float bG = bias[3 * H_ + j0 + ejj];
    float cst = 0.0f;

    // A-frag LDS offsets (u16 units); row stride APE=520 -> conflict-free b128
    const int ar0 = (mh * 32 + l15) * APE + quad * 8;
    const int ar1 = (mh * 32 + 16 + l15) * APE + quad * 8;
    const int srow = w * 8;                 // staging rows w*8..w*8+7
    const int loff = lane * 8;              // 16B per lane

    for (int s = 0; s < T_; ++s) {
        const int t  = dir ? (T_ - 1 - s) : s;
        const int pr = s & 1, pw = pr ^ 1;
        const u16* hbR = hb + (size_t)(pr * 2 + dir) * B_ * H_;

        // 1. stage c0 = x_t (K 0..511) into Ab0 — no dependency on h
        {
            const u16* src = xT + (size_t)t * B_ * D_;
            #pragma unroll
            for (int r = 0; r < 8; ++r)
                gl_lds(src + (srow + r) * D_ + loff, Ab0 + (srow + r) * APE);
        }
        // 2. wait for generation s (hidden under c0 flight), then acquire-invalidate
        if (tid == 0) {
            while (__hip_atomic_load(&cnt[dir], __ATOMIC_RELAXED,
                                     __HIP_MEMORY_SCOPE_AGENT) < WPD * s) { }
        }
        __syncthreads();                                   // drains c0 too
        if (w == 0) __builtin_amdgcn_fence(__ATOMIC_ACQUIRE, "agent");  // inv L1/L2
        __syncthreads();
        // 3. stage c1 = h cols 0..511 (K 512..1023) into Ab1
        #pragma unroll
        for (int r = 0; r < 8; ++r)
            gl_lds(hbR + (srow + r) * H_ + loff, Ab1 + (srow + r) * APE);
        // 4. compute c0 (kh==0 waves: frags 0..15)
        v4f acc0 = {0.f, 0.f, 0.f, 0.f}, acc1 = {0.f, 0.f, 0.f, 0.f};
        if (kh == 0) {
            #pragma unroll
            for (int f = 0; f < 16; ++f) {
                v8bf a0 = *(const v8bf*)(Ab0 + ar0 + f * 32);
                v8bf a1 = *(const v8bf*)(Ab0 + ar1 + f * 32);
                acc0 = MFMA(a0, bfr[f], acc0);
                acc1 = MFMA(a1, bfr[f], acc1);
            }
        }
        __syncthreads();                                   // drains c1
        // 6. stage c2 = h cols 512..1023 (K 1024..1535) into Ab0
        #pragma unroll
        for (int r = 0; r < 8; ++r)
            gl_lds(hbR + (srow + r) * H_ + 512 + loff, Ab0 + (srow + r) * APE);
        // 7. compute c1 from Ab1
        if (kh == 0) {
            #pragma unroll
            for (int f = 16; f < 24; ++f) {
                v8bf a0 = *(const v8bf*)(Ab1 + ar0 + (f - 16) * 32);
                v8bf a1 = *(const v8bf*)(Ab1 + ar1 + (f - 16) * 32);
                acc0 = MFMA(a0, bfr[f], acc0);
                acc1 = MFMA(a1, bfr[f], acc1);
            }
        } else {
            #pragma unroll
            for (int f = 0; f < 8; ++f) {
                v8bf a0 = *(const v8bf*)(Ab1 + ar0 + 256 + f * 32);
                v8bf a1 = *(const v8bf*)(Ab1 + ar1 + 256 + f * 32);
                acc0 = MFMA(a0, bfr[f], acc0);
                acc1 = MFMA(a1, bfr[f], acc1);
            }
        }
        __syncthreads();                                   // drains c2
        // 9. compute c2 (kh==1 waves: frags 8..23)
        if (kh == 1) {
            #pragma unroll
            for (int f = 8; f < 24; ++f) {
                v8bf a0 = *(const v8bf*)(Ab0 + ar0 + (f - 8) * 32);
                v8bf a1 = *(const v8bf*)(Ab0 + ar1 + (f - 8) * 32);
                acc0 = MFMA(a0, bfr[f], acc0);
                acc1 = MFMA(a1, bfr[f], acc1);
            }
        }
        // 10. write partial C tiles (C layout: col = lane&15, row = quad*4+reg)
        {
            float* Cw = Cl + kh * (64 * 33);
            #pragma unroll
            for (int r = 0; r < 4; ++r) {
                Cw[(mh * 32 + quad * 4 + r) * 33 + nt * 16 + l15]      = acc0[r];
                Cw[(mh * 32 + 16 + quad * 4 + r) * 33 + nt * 16 + l15] = acc1[r];
            }
        }
        __syncthreads();
        // 11. epilogue: gates, c, h  (cols: i=0..7, f=8..15, o=16..23, g=24..31)
        {
            const float* C0 = Cl + eb * 33;
            const float* C1 = Cl + 64 * 33 + eb * 33;
            float zi = C0[ejj]      + C1[ejj]      + bI;
            float zf = C0[8 + ejj]  + C1[8 + ejj]  + bF;
            float zo = C0[16 + ejj] + C1[16 + ejj] + bO;
            float zg = C0[24 + ejj] + C1[24 + ejj] + bG;
            float iv = sigm(zi), fv = sigm(zf), ov = sigm(zo), gv = tanh_f(zg);
            float cv = fv * cst + iv * gv; cst = cv;
            float hv = ov * tanh_f(cv);
            hb[(size_t)(pw * 2 + dir) * B_ * H_ + (size_t)eb * H_ + j0 + ejj] = f2bf(hv);
            out[((size_t)eb * T_ + t) * (2 * H_) + dir * H_ + j0 + ejj] = hv;
        }
        // 12. publish: stores already drained by syncthreads; single-wave release + arrive
        __syncthreads();
        if (tid == 0) {
            __builtin_amdgcn_fence(__ATOMIC_RELEASE, "agent");   // wbl2
            __hip_atomic_fetch_add(&cnt[dir], 1, __ATOMIC_RELAXED,
                                   __HIP_MEMORY_SCOPE_AGENT);
        }
    }
}

extern "C" void kernel_launch(void* const* d_in, const int* in_sizes, int n_in,
                              void* d_out, int out_size, void* d_ws, size_t ws_size,
                              hipStream_t stream) {
    const float* xin  = (const float*)d_in[0];
    const float* Wx_f = (const float*)d_in[1];
    const float* Wh_f = (const float*)d_in[2];
    const float* b_f  = (const float*)d_in[3];
    const float* Wx_b = (const float*)d_in[4];
    const float* Wh_b = (const float*)d_in[5];
    const float* b_b  = (const float*)d_in[6];
    float* out = (float*)d_out;

    u16* xT = (u16*)d_ws;                                        // 32 MiB
    u16* hb = (u16*)((char*)d_ws + (size_t)T_ * B_ * D_ * 2);    // 512 KiB
    int* cnt = (int*)((char*)d_ws + (size_t)T_ * B_ * D_ * 2 + 524288);

    hipLaunchKernelGGL(prep_kernel, dim3((B_ * T_ * (D_ / 4)) / 256), dim3(256), 0,
                       stream, xin, xT, hb, cnt);

    hipFuncSetAttribute(reinterpret_cast<const void*>(scan_kernel),
                        hipFuncAttributeMaxDynamicSharedMemorySize, LDS_TOTAL);

    void* args[] = {(void*)&Wx_f, (void*)&Wh_f, (void*)&b_f,
                    (void*)&Wx_b, (void*)&Wh_b, (void*)&b_b,
                    (void*)&xT, (void*)&hb, (void*)&cnt, (void*)&out};
    hipLaunchCooperativeKernel(reinterpret_cast<void*>(scan_kernel),
                               dim3(WGS), dim3(512), args, LDS_TOTAL, stream);
}